// Round 16
// baseline (822.237 us; speedup 1.0000x reference)
//
#include <hip/hip_runtime.h>
#include <hip/hip_bf16.h>
#include <hip/hip_cooperative_groups.h>

namespace cg = cooperative_groups;

#define SEQ 2305
#define NROWS 4610      // B*SEQ
#define MPAD 4736       // NROWS rounded up to 128
#define DIM 512
#define QKVN 1536
#define SMEM_BYTES 25856

typedef __attribute__((ext_vector_type(8))) short v8s;
typedef __attribute__((ext_vector_type(4))) float v4f;

__device__ __forceinline__ float bf2f(unsigned short u) {
    return __uint_as_float(((unsigned)u) << 16);
}

__device__ __forceinline__ void load_lds16(const void* g, void* l) {
    __builtin_amdgcn_global_load_lds(
        (const __attribute__((address_space(1))) void*)g,
        (__attribute__((address_space(3))) void*)l, 16, 0, 0);
}

// ---------------- weight transpose + bf16 cast of x + zero colsum ----------------
struct WPack { const float* p[12]; };
struct BPack { const float* bo[3]; };

__global__ void prep_inputs(WPack wp, __hip_bfloat16* __restrict__ wqkv,
                            __hip_bfloat16* __restrict__ wo,
                            const float4* __restrict__ xin,
                            __hip_bfloat16* __restrict__ xb, int n4,
                            float* __restrict__ colsum) {
    int tx = threadIdx.x, ty = threadIdx.y;
    int m = blockIdx.z;
    if (m == 12) {
        int tidl = ty * 32 + tx;
        int bid = blockIdx.y * 16 + blockIdx.x;
        if (bid == 0) {
            #pragma unroll
            for (int k = 0; k < 4; k++) colsum[k * 256 + tidl] = 0.f;
        }
        for (int i = bid * 256 + tidl; i < n4; i += 65536) {
            float4 v = xin[i];
            int j = i * 4;
            xb[j + 0] = __float2bfloat16(v.x);
            xb[j + 1] = __float2bfloat16(v.y);
            xb[j + 2] = __float2bfloat16(v.z);
            xb[j + 3] = __float2bfloat16(v.w);
        }
        return;
    }
    __shared__ float tile[32][33];
    const float* src = wp.p[m];
    int l = m >> 2, j = m & 3;
    __hip_bfloat16* dst = (j < 3) ? (wqkv + (size_t)l * QKVN * DIM + (size_t)j * DIM * DIM)
                                  : (wo + (size_t)l * DIM * DIM);
    int bx = blockIdx.x * 32, by = blockIdx.y * 32;
    #pragma unroll
    for (int i = 0; i < 4; i++)
        tile[ty + 8 * i][tx] = src[(size_t)(by + ty + 8 * i) * DIM + bx + tx];
    __syncthreads();
    #pragma unroll
    for (int i = 0; i < 4; i++)
        dst[(size_t)(bx + ty + 8 * i) * DIM + by + tx] = __float2bfloat16(tile[tx][ty + 8 * i]);
}

// ================= phase bodies (shared by fused + fallback kernels) =================

// ---- bf16 GEMM 64x128 tile, BK=64 (twin 32-k sub-buffers), LDS-staged A and B ----
__device__ __attribute__((noinline)) void gemm_body(
    char* smemc,
    const __hip_bfloat16* A, const __hip_bfloat16* Bt,
    float* C, const float* bias,
    const __hip_bfloat16* resb, __hip_bfloat16* Cb,
    int M, int N, float* colsum, int v, int tilesX) {
    short* As0 = (short*)smemc;          // 64*32
    short* As1 = As0 + 2048;
    short* Bs0 = As1 + 2048;             // 128*32
    short* Bs1 = Bs0 + 4096;
    const int K = 512;
    int tid = threadIdx.x;
    int wid = tid >> 6, lane = tid & 63;
    int quad = lane >> 4, l16 = lane & 15;
    int bM = (v % tilesX) * 64, bN = (v / tilesX) * 128;
    int wM = (wid >> 1) * 32, wN = (wid & 1) * 64;

    const short* Ag = (const short*)A;
    const short* Bg = (const short*)Bt;

    int rowS = tid >> 2, cg0 = tid & 3;
    const short* gA = Ag + (size_t)(bM + rowS) * K + cg0 * 8;
    const short* gB0 = Bg + (size_t)(bN + rowS) * K + cg0 * 8;
    const short* gB1 = Bg + (size_t)(bN + 64 + rowS) * K + cg0 * 8;

    v4f acc[2][4] = {};
    for (int k0 = 0; k0 < K; k0 += 64) {
        load_lds16(gA + k0, As0 + wid * 512);
        load_lds16(gB0 + k0, Bs0 + wid * 512);
        load_lds16(gB1 + k0, Bs0 + 2048 + wid * 512);
        load_lds16(gA + k0 + 32, As1 + wid * 512);
        load_lds16(gB0 + k0 + 32, Bs1 + wid * 512);
        load_lds16(gB1 + k0 + 32, Bs1 + 2048 + wid * 512);
        __syncthreads();
        #pragma unroll
        for (int s = 0; s < 2; s++) {
            const short* Asp = s ? As1 : As0;
            const short* Bsp = s ? Bs1 : Bs0;
            v8s af[2], bf[4];
            #pragma unroll
            for (int i = 0; i < 2; i++)
                af[i] = *(const v8s*)(Asp + (wM + i * 16 + l16) * 32 + quad * 8);
            #pragma unroll
            for (int j = 0; j < 4; j++)
                bf[j] = *(const v8s*)(Bsp + (wN + j * 16 + l16) * 32 + quad * 8);
            #pragma unroll
            for (int i = 0; i < 2; i++)
                #pragma unroll
                for (int j = 0; j < 4; j++)
                    acc[i][j] = __builtin_amdgcn_mfma_f32_16x16x32_bf16(af[i], bf[j], acc[i][j], 0, 0, 0);
        }
        __syncthreads();
    }

    const unsigned short* resu = (const unsigned short*)resb;
    #pragma unroll
    for (int i = 0; i < 2; i++) {
        int row = bM + wM + i * 16 + quad * 4;
        #pragma unroll
        for (int j = 0; j < 4; j++) {
            int col = bN + wN + j * 16 + l16;
            #pragma unroll
            for (int r = 0; r < 4; r++) {
                int rr = row + r;
                if (rr < M) {
                    float vv = acc[i][j][r];
                    if (bias) vv += bias[col];
                    size_t idx = (size_t)rr * N + col;
                    if (resu) vv += bf2f(resu[idx]);
                    if (C) C[idx] = vv;
                    if (Cb) Cb[idx] = __float2bfloat16(vv);
                }
            }
        }
    }

    if (colsum) {
        #pragma unroll
        for (int j = 0; j < 4; j++) {
            int col = bN + wN + j * 16 + l16;
            if (col >= 1024) {
                float s0 = 0.f, s1 = 0.f;
                #pragma unroll
                for (int i = 0; i < 2; i++) {
                    int row = bM + wM + i * 16 + quad * 4;
                    #pragma unroll
                    for (int r = 0; r < 4; r++) {
                        int rr = row + r;
                        if (rr < M) {
                            float vv = acc[i][j][r];
                            if (rr >= SEQ) s1 += vv; else s0 += vv;
                        }
                    }
                }
                s0 += __shfl_xor(s0, 16); s0 += __shfl_xor(s0, 32);
                s1 += __shfl_xor(s1, 16); s1 += __shfl_xor(s1, 32);
                if (quad == 0) {
                    if (s0 != 0.f) atomicAdd(&colsum[col - 1024], s0);
                    if (s1 != 0.f) atomicAdd(&colsum[512 + col - 1024], s1);
                }
            }
        }
    }
}

// ---- axial attention body ----
__device__ __attribute__((noinline)) void axial_body(
    char* smemc, const unsigned short* qkvb, __hip_bfloat16* attn_b, int typ, int v) {
    short* Ks = (short*)smemc;                 // 64*64
    short* Vs = Ks + 4096;                     // 64*64
    short* Ps = Vs + 4096;                     // 64*72
    float* invl = (float*)(smemc + 25600);     // 64

    int tid = threadIdx.x;
    int wid = tid >> 6, lane = tid & 63;
    int quad = lane >> 4, l16 = lane & 15;
    int n = v % 48;
    int bh = v / 48;
    int b = bh >> 3, h = bh & 7;
    size_t rowbase = (size_t)b * SEQ;
    int hoff = h * 64;

    __syncthreads();   // guard: smem reuse across virtual tiles

    #pragma unroll
    for (int it = 0; it < 2; it++) {
        int linear = it * 256 + tid;
        int slot = linear >> 3;
        int cd = linear & 7;
        int cs = cd ^ (slot & 7);
        int sp = (slot == 0) ? 0
               : (slot <= 48 ? (typ == 0 ? 1 + n * 48 + (slot - 1) : 1 + (slot - 1) * 48 + n) : 0);
        const unsigned short* srcK = qkvb + (rowbase + sp) * QKVN + hoff + 512 + cs * 8;
        load_lds16(srcK, Ks + it * 2048 + wid * 512 + lane * 8);
        const unsigned short* srcV = qkvb + (rowbase + sp) * QKVN + hoff + 1024 + cd * 8;
        load_lds16(srcV, Vs + it * 2048 + wid * 512 + lane * 8);
    }

    int qi = wid * 16 + l16;
    int sp_q = (qi >= 1 && qi <= 48)
             ? (typ == 0 ? 1 + n * 48 + (qi - 1) : 1 + (qi - 1) * 48 + n) : 0;
    const unsigned short* qptr = qkvb + (rowbase + sp_q) * QKVN + hoff + quad * 8;
    v8s qa0 = *(const v8s*)qptr;
    v8s qa1 = *(const v8s*)(qptr + 32);

    __syncthreads();

    if (n == 0 && tid < 64) {
        attn_b[rowbase * DIM + hoff + tid] =
            __float2bfloat16(bf2f(qkvb[rowbase * QKVN + hoff + 1024 + tid]));
    }

    v4f st[4];
    #pragma unroll
    for (int kt = 0; kt < 4; kt++) {
        int slot = kt * 16 + l16;
        int s7 = slot & 7;
        v8s blo = *(const v8s*)(Ks + slot * 64 + ((quad ^ s7) * 8));
        v8s bhi = *(const v8s*)(Ks + slot * 64 + (((4 + quad) ^ s7) * 8));
        v4f a = {};
        a = __builtin_amdgcn_mfma_f32_16x16x32_bf16(qa0, blo, a, 0, 0, 0);
        a = __builtin_amdgcn_mfma_f32_16x16x32_bf16(qa1, bhi, a, 0, 0, 0);
        st[kt] = a;
    }

    const float NEG = -3.0e38f;
    float sv[4][4];
    float pm[4] = {NEG, NEG, NEG, NEG};
    #pragma unroll
    for (int kt = 0; kt < 4; kt++) {
        int j = kt * 16 + l16;
        #pragma unroll
        for (int r = 0; r < 4; r++) {
            int i = wid * 16 + quad * 4 + r;
            bool ok = (i >= 1) && (i <= 48) && (j <= i);
            float vv = ok ? st[kt][r] * 0.125f : NEG;
            sv[kt][r] = vv;
            pm[r] = fmaxf(pm[r], vv);
        }
    }
    #pragma unroll
    for (int r = 0; r < 4; r++)
        for (int o = 1; o < 16; o <<= 1) pm[r] = fmaxf(pm[r], __shfl_xor(pm[r], o));

    float ps[4] = {0.f, 0.f, 0.f, 0.f};
    #pragma unroll
    for (int kt = 0; kt < 4; kt++) {
        int j = kt * 16 + l16;
        #pragma unroll
        for (int r = 0; r < 4; r++) {
            float e = __expf(sv[kt][r] - pm[r]);
            ps[r] += e;
            Ps[(wid * 16 + quad * 4 + r) * 72 + j] = (short)__bfloat16_as_ushort(__float2bfloat16(e));
        }
    }
    #pragma unroll
    for (int r = 0; r < 4; r++)
        for (int o = 1; o < 16; o <<= 1) ps[r] += __shfl_xor(ps[r], o);
    if (l16 == 0) {
        #pragma unroll
        for (int r = 0; r < 4; r++)
            invl[wid * 16 + quad * 4 + r] = 1.0f / ps[r];
    }
    __syncthreads();

    #pragma unroll
    for (int qt = 0; qt < 4; qt++) {
        v4f oc = {};
        #pragma unroll
        for (int kc = 0; kc < 2; kc++) {
            v8s pa = *(const v8s*)(Ps + (qt * 16 + l16) * 72 + kc * 32 + quad * 8);
            v8s bfr;
            #pragma unroll
            for (int jj = 0; jj < 8; jj++)
                bfr[jj] = Vs[(kc * 32 + quad * 8 + jj) * 64 + wid * 16 + l16];
            oc = __builtin_amdgcn_mfma_f32_16x16x32_bf16(pa, bfr, oc, 0, 0, 0);
        }
        #pragma unroll
        for (int r = 0; r < 4; r++) {
            int i = qt * 16 + quad * 4 + r;
            if (i >= 1 && i <= 48) {
                int sp = typ == 0 ? 1 + n * 48 + (i - 1) : 1 + (i - 1) * 48 + n;
                attn_b[(rowbase + sp) * DIM + hoff + wid * 16 + l16] =
                    __float2bfloat16(oc[r] * invl[i]);
            }
        }
    }
}

// ---- nearby attention body (v in [0,2306): 2304 tiles + 2 special blocks) ----
__device__ __attribute__((noinline)) void nearby_body(
    char* smemc, const unsigned short* qkvb, const float* colsum,
    __hip_bfloat16* attn_b, int v) {
    short* Vs = (short*)smemc;                          // 128*64
    __hip_bfloat16* Ps = (__hip_bfloat16*)(smemc + 16384);  // 16*264
    float* redm = (float*)(smemc + 24832);              // 64
    float* reds = redm + 64;                            // 64

    int tid = threadIdx.x;
    int wid = tid >> 6, lane = tid & 63;
    int quad = lane >> 4, l16 = lane & 15;

    if (v >= 2304) {
        int b = v - 2304;
        size_t rb = (size_t)b * SEQ;
        for (int c = tid; c < 512; c += 256) {
            attn_b[(rb + 2304) * DIM + c] =
                __float2bfloat16(colsum[b * 512 + c] * (1.0f / 2305.0f));
            attn_b[rb * DIM + c] =
                __float2bfloat16(bf2f(qkvb[rb * QKVN + 1024 + c]));
        }
        return;
    }

    int bh = v & 15;
    int tile = v >> 4;
    int b = bh >> 3, h = bh & 7;
    int t = tile >> 4;
    int sxy = tile & 15;
    int hh0 = (sxy >> 2) * 4, ww0 = (sxy & 3) * 4;
    int nf = (t < 3 ? t : 3) + 1;
    int t0 = t - (nf - 1);
    size_t rowbase = (size_t)b * SEQ;
    int hoff = h * 64;

    auto slot_kp = [&](int slot) -> int {
        int f = slot >> 6, uy = (slot >> 3) & 7, ux = slot & 7;
        int kh = hh0 - 2 + uy, kw = ww0 - 2 + ux;
        int kt = t0 + f;
        bool ok = (kh >= 0) && (kh < 16) && (kw >= 0) && (kw < 16) && (f < nf);
        return ok ? (kt * 256 + kh * 16 + kw + 1) : 0;
    };

    __syncthreads();   // guard: smem reuse across virtual tiles

    int qp_f = t * 256 + (hh0 + (l16 >> 2)) * 16 + (ww0 + (l16 & 3));
    const unsigned short* qptr = qkvb + (rowbase + qp_f) * QKVN + hoff + quad * 8;
    v8s qa0 = *(const v8s*)qptr;
    v8s qa1 = *(const v8s*)(qptr + 32);

    v8s kb_lo[4], kb_hi[4];
    #pragma unroll
    for (int k = 0; k < 4; k++) {
        int slot = (wid * 4 + k) * 16 + l16;
        int kp = slot_kp(slot);
        const unsigned short* kr = qkvb + (rowbase + kp) * QKVN + hoff + 512;
        kb_lo[k] = *(const v8s*)(kr + quad * 8);
        kb_hi[k] = *(const v8s*)(kr + 32 + quad * 8);
    }

    #pragma unroll
    for (int it = 0; it < 4; it++) {
        int linear = it * 256 + tid;
        int slot = linear >> 3;
        int cd = linear & 7;
        int cs = cd ^ ((slot >> 3) & 7);
        int kp = slot_kp(slot);
        const unsigned short* src = qkvb + (rowbase + kp) * QKVN + hoff + 1024 + cs * 8;
        load_lds16(src, Vs + it * 2048 + wid * 512 + lane * 8);
    }

    v4f st[4];
    #pragma unroll
    for (int k = 0; k < 4; k++) {
        v4f a = {};
        a = __builtin_amdgcn_mfma_f32_16x16x32_bf16(qa0, kb_lo[k], a, 0, 0, 0);
        a = __builtin_amdgcn_mfma_f32_16x16x32_bf16(qa1, kb_hi[k], a, 0, 0, 0);
        st[k] = a;
    }

    const float NEG = -3.0e38f;
    float sv[4][4];
    float pm[4] = {NEG, NEG, NEG, NEG};
    #pragma unroll
    for (int k = 0; k < 4; k++) {
        int slot = (wid * 4 + k) * 16 + l16;
        int f = slot >> 6, uy = (slot >> 3) & 7, ux = slot & 7;
        int kh = hh0 - 2 + uy, kw = ww0 - 2 + ux;
        bool okb = (kh >= 0) && (kh < 16) && (kw >= 0) && (kw < 16) && (f < nf);
        int dyp2 = uy - quad;
        bool oky = okb && (dyp2 >= 0) && (dyp2 <= 4);
        #pragma unroll
        for (int r = 0; r < 4; r++) {
            int dxp2 = ux - r;
            bool ok = oky && (dxp2 >= 0) && (dxp2 <= 4);
            if (f == nf - 1) ok = ok && (dyp2 * 5 + dxp2 < 12);
            float vv = ok ? st[k][r] * 0.125f : NEG;
            sv[k][r] = vv;
            pm[r] = fmaxf(pm[r], vv);
        }
    }
    #pragma unroll
    for (int r = 0; r < 4; r++)
        for (int o = 1; o < 16; o <<= 1) pm[r] = fmaxf(pm[r], __shfl_xor(pm[r], o));
    if (l16 == 0) {
        #pragma unroll
        for (int r = 0; r < 4; r++) redm[(quad * 4 + r) * 4 + wid] = pm[r];
    }
    __syncthreads();   // redm visible, V half-0 staged

    float rm[4];
    #pragma unroll
    for (int r = 0; r < 4; r++) {
        int row = (quad * 4 + r) * 4;
        rm[r] = fmaxf(fmaxf(redm[row], redm[row + 1]), fmaxf(redm[row + 2], redm[row + 3]));
    }

    float ps[4] = {0.f, 0.f, 0.f, 0.f};
    #pragma unroll
    for (int k = 0; k < 4; k++) {
        int slot = (wid * 4 + k) * 16 + l16;
        #pragma unroll
        for (int r = 0; r < 4; r++) {
            float e = __expf(sv[k][r] - rm[r]);
            ps[r] += e;
            Ps[(quad * 4 + r) * 264 + slot] = __float2bfloat16(e);
        }
    }
    #pragma unroll
    for (int r = 0; r < 4; r++)
        for (int o = 1; o < 16; o <<= 1) ps[r] += __shfl_xor(ps[r], o);
    if (l16 == 0) {
        #pragma unroll
        for (int r = 0; r < 4; r++) reds[(quad * 4 + r) * 4 + wid] = ps[r];
    }
    __syncthreads();   // Ps + reds visible

    float inv[4];
    #pragma unroll
    for (int r = 0; r < 4; r++) {
        int row = (quad * 4 + r) * 4;
        float d = reds[row] + reds[row + 1] + reds[row + 2] + reds[row + 3];
        inv[r] = 1.0f / d;
    }

    int dcol = wid * 16 + l16;
    int c_r = dcol >> 3, d7 = dcol & 7;
    v4f oc = {};
    #pragma unroll
    for (int kc = 0; kc < 4; kc++) {
        v8s pa = *(const v8s*)((const short*)Ps + l16 * 264 + kc * 32 + quad * 8);
        v8s bf;
        #pragma unroll
        for (int j = 0; j < 8; j++) {
            int slot = kc * 32 + quad * 8 + j;
            int key = (slot >> 3) & 7;
            bf[j] = Vs[(slot & 127) * 64 + ((c_r ^ key) * 8) + d7];
        }
        oc = __builtin_amdgcn_mfma_f32_16x16x32_bf16(pa, bf, oc, 0, 0, 0);
    }
    __syncthreads();   // half-0 reads done

    #pragma unroll
    for (int it = 0; it < 4; it++) {
        int linear = 1024 + it * 256 + tid;
        int slot = linear >> 3;
        int cd = linear & 7;
        int cs = cd ^ ((slot >> 3) & 7);
        int kp = slot_kp(slot);
        const unsigned short* src = qkvb + (rowbase + kp) * QKVN + hoff + 1024 + cs * 8;
        load_lds16(src, Vs + it * 2048 + wid * 512 + lane * 8);
    }
    __syncthreads();   // half-1 staged

    #pragma unroll
    for (int kc = 4; kc < 8; kc++) {
        v8s pa = *(const v8s*)((const short*)Ps + l16 * 264 + kc * 32 + quad * 8);
        v8s bf;
        #pragma unroll
        for (int j = 0; j < 8; j++) {
            int slot = kc * 32 + quad * 8 + j;
            int key = (slot >> 3) & 7;
            bf[j] = Vs[(slot & 127) * 64 + ((c_r ^ key) * 8) + d7];
        }
        oc = __builtin_amdgcn_mfma_f32_16x16x32_bf16(pa, bf, oc, 0, 0, 0);
    }

    #pragma unroll
    for (int r = 0; r < 4; r++) {
        int qp = t * 256 + (hh0 + quad) * 16 + (ww0 + r);
        if (qp != 0) {
            attn_b[(rowbase + qp) * DIM + hoff + dcol] =
                __float2bfloat16(oc[r] * inv[r]);
        }
    }
}

// ================= fused persistent cooperative kernel =================
__global__ __launch_bounds__(256) void fused_layers(
    __hip_bfloat16* xb, const __hip_bfloat16* wqkv, const __hip_bfloat16* wo,
    __hip_bfloat16* qkvb, __hip_bfloat16* attnb, float* colsum, float* xcur, BPack bp) {
    __shared__ __align__(16) char smem[SMEM_BYTES];
    cg::grid_group grid = cg::this_grid();
    const int G = gridDim.x;
    for (int l = 0; l < 3; l++) {
        const __hip_bfloat16* wq = wqkv + (size_t)l * QKVN * DIM;
        for (int v = blockIdx.x; v < 74 * 12; v += G)
            gemm_body(smem, xb, wq, nullptr, nullptr, nullptr, qkvb, NROWS, QKVN,
                      (l == 2) ? colsum : nullptr, v, 74);
        __threadfence();
        grid.sync();
        if (l < 2) {
            for (int v = blockIdx.x; v < 768; v += G)
                axial_body(smem, (const unsigned short*)qkvb, attnb, l, v);
        } else {
            for (int v = blockIdx.x; v < 2306; v += G)
                nearby_body(smem, (const unsigned short*)qkvb, colsum, attnb, v);
        }
        __threadfence();
        grid.sync();
        const __hip_bfloat16* wl = wo + (size_t)l * DIM * DIM;
        if (l < 2) {
            for (int v = blockIdx.x; v < 74 * 4; v += G)
                gemm_body(smem, attnb, wl, nullptr, bp.bo[l], xb, xb, NROWS, DIM, nullptr, v, 74);
            __threadfence();
            grid.sync();
        } else {
            for (int v = blockIdx.x; v < 74 * 4; v += G)
                gemm_body(smem, attnb, wl, xcur, bp.bo[2], xb, nullptr, NROWS, DIM, nullptr, v, 74);
        }
    }
}

// ================= fallback wrappers (R15-equivalent path) =================
__global__ __launch_bounds__(256) void gemm_k(
    const __hip_bfloat16* A, const __hip_bfloat16* Bt, float* C, const float* bias,
    const __hip_bfloat16* resb, __hip_bfloat16* Cb, int M, int N, float* colsum, int tilesX) {
    __shared__ __align__(16) char smem[24576];
    gemm_body(smem, A, Bt, C, bias, resb, Cb, M, N, colsum, blockIdx.x, tilesX);
}
__global__ __launch_bounds__(256) void axial_k(
    const unsigned short* qkvb, __hip_bfloat16* attn_b, int typ) {
    __shared__ __align__(16) char smem[SMEM_BYTES];
    axial_body(smem, qkvb, attn_b, typ, blockIdx.x);
}
__global__ __launch_bounds__(256) void nearby_k(
    const unsigned short* qkvb, const float* colsum, __hip_bfloat16* attn_b) {
    __shared__ __align__(16) char smem[25344];
    nearby_body(smem, qkvb, colsum, attn_b, blockIdx.x);
}

// ---------------- host launch ----------------
extern "C" void kernel_launch(void* const* d_in, const int* in_sizes, int n_in,
                              void* d_out, int out_size, void* d_ws, size_t ws_size,
                              hipStream_t stream) {
    const float* x = (const float*)d_in[0];
    float* xcur = (float*)d_out;

    char* ws = (char*)d_ws;
    size_t off = 0;
    auto alloc = [&](size_t bytes) -> void* {
        void* p = ws + off;
        off = (off + bytes + 255) & ~(size_t)255;
        return p;
    };
    __hip_bfloat16* wqkv  = (__hip_bfloat16*)alloc((size_t)3 * QKVN * DIM * 2);
    __hip_bfloat16* wo    = (__hip_bfloat16*)alloc((size_t)3 * DIM * DIM * 2);
    __hip_bfloat16* xb    = (__hip_bfloat16*)alloc((size_t)MPAD * DIM * 2);
    __hip_bfloat16* attnb = (__hip_bfloat16*)alloc((size_t)MPAD * DIM * 2);
    float* colsum         = (float*)alloc((size_t)2 * 512 * 4);
    __hip_bfloat16* qkvb  = (__hip_bfloat16*)alloc((size_t)NROWS * QKVN * 2);

    const int nElem = NROWS * DIM;
    const int n4 = nElem / 4;

    WPack wp;
    for (int l = 0; l < 3; l++)
        for (int j = 0; j < 4; j++)
            wp.p[l * 4 + j] = (const float*)d_in[2 + l * 5 + j];
    prep_inputs<<<dim3(16, 16, 13), dim3(32, 8), 0, stream>>>(
        wp, wqkv, wo, (const float4*)x, xb, n4, colsum);

    BPack bp;
    for (int l = 0; l < 3; l++) bp.bo[l] = (const float*)d_in[6 + l * 5];

    // try cooperative fused path
    hipError_t err = hipErrorUnknown;
    int nb = 0;
    if (hipOccupancyMaxActiveBlocksPerMultiprocessor(&nb, fused_layers, 256, 0) == hipSuccess
        && nb > 0) {
        hipDeviceProp_t prop;
        int dev = 0;
        hipGetDevice(&dev);
        if (hipGetDeviceProperties(&prop, dev) == hipSuccess) {
            int G = nb * prop.multiProcessorCount;
            if (G > 2306) G = 2306;
            void* args[] = { (void*)&xb, (void*)&wqkv, (void*)&wo, (void*)&qkvb,
                             (void*)&attnb, (void*)&colsum, (void*)&xcur, (void*)&bp };
            err = hipLaunchCooperativeKernel((void*)fused_layers, dim3(G), dim3(256),
                                             args, 0, stream);
        }
    }
    if (err != hipSuccess) {
        // fallback: R15-style multi-kernel path (same bodies)
        for (int l = 0; l < 3; l++) {
            gemm_k<<<74 * 12, 256, 0, stream>>>(
                xb, wqkv + (size_t)l * QKVN * DIM, nullptr, nullptr, nullptr, qkvb,
                NROWS, QKVN, l == 2 ? colsum : nullptr, 74);
            if (l < 2) {
                axial_k<<<768, 256, 0, stream>>>((const unsigned short*)qkvb, attnb, l);
            } else {
                nearby_k<<<2306, 256, 0, stream>>>((const unsigned short*)qkvb, colsum, attnb);
            }
            if (l < 2) {
                gemm_k<<<74 * 4, 256, 0, stream>>>(
                    attnb, wo + (size_t)l * DIM * DIM, nullptr, bp.bo[l], xb, xb,
                    NROWS, DIM, nullptr, 74);
            } else {
                gemm_k<<<74 * 4, 256, 0, stream>>>(
                    attnb, wo + (size_t)l * DIM * DIM, xcur, bp.bo[2], xb, nullptr,
                    NROWS, DIM, nullptr, 74);
            }
        }
    }
}

// Round 17
// 259.484 us; speedup vs baseline: 3.1687x; 3.1687x over previous
//
#include <hip/hip_runtime.h>
#include <hip/hip_bf16.h>

#define SEQ 2305
#define NROWS 4610      // B*SEQ
#define MPAD 4736       // NROWS rounded up to 128
#define DIM 512
#define QKVN 1536

typedef __attribute__((ext_vector_type(8))) short v8s;
typedef __attribute__((ext_vector_type(4))) float v4f;

__device__ __forceinline__ float bf2f(unsigned short u) {
    return __uint_as_float(((unsigned)u) << 16);
}

__device__ __forceinline__ void load_lds16(const void* g, void* l) {
    __builtin_amdgcn_global_load_lds(
        (const __attribute__((address_space(1))) void*)g,
        (__attribute__((address_space(3))) void*)l, 16, 0, 0);
}

// ---------------- weight transpose + bf16 cast of x + zero colsum ----------------
struct WPack { const float* p[12]; };

__global__ void prep_inputs(WPack wp, __hip_bfloat16* __restrict__ wqkv,
                            __hip_bfloat16* __restrict__ wo,
                            const float4* __restrict__ xin,
                            __hip_bfloat16* __restrict__ xb, int n4,
                            float* __restrict__ colsum) {
    int tx = threadIdx.x, ty = threadIdx.y;
    int m = blockIdx.z;
    if (m == 12) {   // cast x -> xb (bf16), grid-stride; block 0 zeroes colsum
        int tidl = ty * 32 + tx;
        int bid = blockIdx.y * 16 + blockIdx.x;
        if (bid == 0) {
            #pragma unroll
            for (int k = 0; k < 4; k++) colsum[k * 256 + tidl] = 0.f;
        }
        for (int i = bid * 256 + tidl; i < n4; i += 65536) {
            float4 v = xin[i];
            int j = i * 4;
            xb[j + 0] = __float2bfloat16(v.x);
            xb[j + 1] = __float2bfloat16(v.y);
            xb[j + 2] = __float2bfloat16(v.z);
            xb[j + 3] = __float2bfloat16(v.w);
        }
        return;
    }
    __shared__ float tile[32][33];
    const float* src = wp.p[m];
    int l = m >> 2, j = m & 3;
    __hip_bfloat16* dst = (j < 3) ? (wqkv + (size_t)l * QKVN * DIM + (size_t)j * DIM * DIM)
                                  : (wo + (size_t)l * DIM * DIM);
    int bx = blockIdx.x * 32, by = blockIdx.y * 32;
    #pragma unroll
    for (int i = 0; i < 4; i++)
        tile[ty + 8 * i][tx] = src[(size_t)(by + ty + 8 * i) * DIM + bx + tx];
    __syncthreads();
    #pragma unroll
    for (int i = 0; i < 4; i++)
        dst[(size_t)(bx + ty + 8 * i) * DIM + by + tx] = __float2bfloat16(tile[tx][ty + 8 * i]);
}

// ---------------- LDS-staged bf16 GEMM, 64x128 tile, BK=64 (twin 32-k sub-buffers) ----------------
// res (bf16) optional; C (fp32) optional; Cb (bf16) optional;
// colsum optional: atomic per-b column sums for cols >= 1024 (V block of QKV).
__global__ __launch_bounds__(256) void gemm_lds(
    const __hip_bfloat16* __restrict__ A, const __hip_bfloat16* __restrict__ Bt,
    float* __restrict__ C, const float* __restrict__ bias,
    const __hip_bfloat16* __restrict__ resb, __hip_bfloat16* __restrict__ Cb,
    int M, int N, float* __restrict__ colsum) {
    __shared__ short As[2][64 * 32];    // 8 KB
    __shared__ short Bs[2][128 * 32];   // 16 KB
    const int K = 512;
    int tid = threadIdx.x;
    int wid = tid >> 6, lane = tid & 63;
    int quad = lane >> 4, l16 = lane & 15;
    int bM = blockIdx.x * 64, bN = blockIdx.y * 128;
    int wM = (wid >> 1) * 32, wN = (wid & 1) * 64;

    const short* Ag = (const short*)A;
    const short* Bg = (const short*)Bt;

    int rowS = tid >> 2, cg = tid & 3;
    const short* gA = Ag + (size_t)(bM + rowS) * K + cg * 8;
    const short* gB0 = Bg + (size_t)(bN + rowS) * K + cg * 8;
    const short* gB1 = Bg + (size_t)(bN + 64 + rowS) * K + cg * 8;

    v4f acc[2][4] = {};
    for (int k0 = 0; k0 < K; k0 += 64) {
        #pragma unroll
        for (int s = 0; s < 2; s++) {
            load_lds16(gA + k0 + s * 32, As[s] + wid * 512);
            load_lds16(gB0 + k0 + s * 32, Bs[s] + wid * 512);
            load_lds16(gB1 + k0 + s * 32, Bs[s] + 2048 + wid * 512);
        }
        __syncthreads();
        #pragma unroll
        for (int s = 0; s < 2; s++) {
            v8s af[2], bf[4];
            #pragma unroll
            for (int i = 0; i < 2; i++)
                af[i] = *(const v8s*)(As[s] + (wM + i * 16 + l16) * 32 + quad * 8);
            #pragma unroll
            for (int j = 0; j < 4; j++)
                bf[j] = *(const v8s*)(Bs[s] + (wN + j * 16 + l16) * 32 + quad * 8);
            #pragma unroll
            for (int i = 0; i < 2; i++)
                #pragma unroll
                for (int j = 0; j < 4; j++)
                    acc[i][j] = __builtin_amdgcn_mfma_f32_16x16x32_bf16(af[i], bf[j], acc[i][j], 0, 0, 0);
        }
        __syncthreads();
    }

    const unsigned short* resu = (const unsigned short*)resb;
    #pragma unroll
    for (int i = 0; i < 2; i++) {
        int row = bM + wM + i * 16 + quad * 4;
        #pragma unroll
        for (int j = 0; j < 4; j++) {
            int col = bN + wN + j * 16 + l16;
            #pragma unroll
            for (int r = 0; r < 4; r++) {
                int rr = row + r;
                if (rr < M) {
                    float v = acc[i][j][r];
                    if (bias) v += bias[col];
                    size_t idx = (size_t)rr * N + col;
                    if (resu) v += bf2f(resu[idx]);
                    if (C) C[idx] = v;
                    if (Cb) Cb[idx] = __float2bfloat16(v);
                }
            }
        }
    }

    // V-column partial sums (for the all-masked nearby row): cols >= 1024
    if (colsum) {
        #pragma unroll
        for (int j = 0; j < 4; j++) {
            int col = bN + wN + j * 16 + l16;
            if (col >= 1024) {
                float s0 = 0.f, s1 = 0.f;
                #pragma unroll
                for (int i = 0; i < 2; i++) {
                    int row = bM + wM + i * 16 + quad * 4;
                    #pragma unroll
                    for (int r = 0; r < 4; r++) {
                        int rr = row + r;
                        if (rr < M) {
                            float v = acc[i][j][r];
                            if (rr >= SEQ) s1 += v; else s0 += v;
                        }
                    }
                }
                // reduce across quads (lanes sharing same col within the wave)
                s0 += __shfl_xor(s0, 16); s0 += __shfl_xor(s0, 32);
                s1 += __shfl_xor(s1, 16); s1 += __shfl_xor(s1, 32);
                if (quad == 0) {
                    if (s0 != 0.f) atomicAdd(&colsum[col - 1024], s0);
                    if (s1 != 0.f) atomicAdd(&colsum[512 + col - 1024], s1);
                }
            }
        }
    }
}

// ---------------- axial attention, flash-style MFMA ----------------
__global__ __launch_bounds__(256) void axial_flash(
    const unsigned short* __restrict__ qkvb, __hip_bfloat16* __restrict__ attn_b, int typ) {
    __shared__ short Ks[64 * 64];    // 8 KB, chunk-XOR swizzled
    __shared__ short Vs[64 * 64];    // 8 KB, linear
    __shared__ short Ps[64 * 72];    // 9 KB
    __shared__ float invl[64];

    int tid = threadIdx.x;
    int wid = tid >> 6, lane = tid & 63;
    int quad = lane >> 4, l16 = lane & 15;
    int n = blockIdx.x;
    int b = blockIdx.y >> 3, h = blockIdx.y & 7;
    size_t rowbase = (size_t)b * SEQ;
    int hoff = h * 64;

    #pragma unroll
    for (int it = 0; it < 2; it++) {
        int linear = it * 256 + tid;
        int slot = linear >> 3;
        int cd = linear & 7;
        int cs = cd ^ (slot & 7);
        int sp = (slot == 0) ? 0
               : (slot <= 48 ? (typ == 0 ? 1 + n * 48 + (slot - 1) : 1 + (slot - 1) * 48 + n) : 0);
        const unsigned short* srcK = qkvb + (rowbase + sp) * QKVN + hoff + 512 + cs * 8;
        load_lds16(srcK, Ks + it * 2048 + wid * 512 + lane * 8);
        const unsigned short* srcV = qkvb + (rowbase + sp) * QKVN + hoff + 1024 + cd * 8;
        load_lds16(srcV, Vs + it * 2048 + wid * 512 + lane * 8);
    }

    int qi = wid * 16 + l16;
    int sp_q = (qi >= 1 && qi <= 48)
             ? (typ == 0 ? 1 + n * 48 + (qi - 1) : 1 + (qi - 1) * 48 + n) : 0;
    const unsigned short* qptr = qkvb + (rowbase + sp_q) * QKVN + hoff + quad * 8;
    v8s qa0 = *(const v8s*)qptr;
    v8s qa1 = *(const v8s*)(qptr + 32);

    __syncthreads();

    if (n == 0 && tid < 64) {
        attn_b[rowbase * DIM + hoff + tid] =
            __float2bfloat16(bf2f(qkvb[rowbase * QKVN + hoff + 1024 + tid]));
    }

    v4f st[4];
    #pragma unroll
    for (int kt = 0; kt < 4; kt++) {
        int slot = kt * 16 + l16;
        int s7 = slot & 7;
        v8s blo = *(const v8s*)(Ks + slot * 64 + ((quad ^ s7) * 8));
        v8s bhi = *(const v8s*)(Ks + slot * 64 + (((4 + quad) ^ s7) * 8));
        v4f a = {};
        a = __builtin_amdgcn_mfma_f32_16x16x32_bf16(qa0, blo, a, 0, 0, 0);
        a = __builtin_amdgcn_mfma_f32_16x16x32_bf16(qa1, bhi, a, 0, 0, 0);
        st[kt] = a;
    }

    const float NEG = -3.0e38f;
    float sv[4][4];
    float pm[4] = {NEG, NEG, NEG, NEG};
    #pragma unroll
    for (int kt = 0; kt < 4; kt++) {
        int j = kt * 16 + l16;
        #pragma unroll
        for (int r = 0; r < 4; r++) {
            int i = wid * 16 + quad * 4 + r;
            bool ok = (i >= 1) && (i <= 48) && (j <= i);
            float v = ok ? st[kt][r] * 0.125f : NEG;
            sv[kt][r] = v;
            pm[r] = fmaxf(pm[r], v);
        }
    }
    #pragma unroll
    for (int r = 0; r < 4; r++)
        for (int o = 1; o < 16; o <<= 1) pm[r] = fmaxf(pm[r], __shfl_xor(pm[r], o));

    float ps[4] = {0.f, 0.f, 0.f, 0.f};
    #pragma unroll
    for (int kt = 0; kt < 4; kt++) {
        int j = kt * 16 + l16;
        #pragma unroll
        for (int r = 0; r < 4; r++) {
            float e = __expf(sv[kt][r] - pm[r]);
            ps[r] += e;
            Ps[(wid * 16 + quad * 4 + r) * 72 + j] = (short)__bfloat16_as_ushort(__float2bfloat16(e));
        }
    }
    #pragma unroll
    for (int r = 0; r < 4; r++)
        for (int o = 1; o < 16; o <<= 1) ps[r] += __shfl_xor(ps[r], o);
    if (l16 == 0) {
        #pragma unroll
        for (int r = 0; r < 4; r++)
            invl[wid * 16 + quad * 4 + r] = 1.0f / ps[r];
    }
    __syncthreads();

    #pragma unroll
    for (int qt = 0; qt < 4; qt++) {
        v4f oc = {};
        #pragma unroll
        for (int kc = 0; kc < 2; kc++) {
            v8s pa = *(const v8s*)(Ps + (qt * 16 + l16) * 72 + kc * 32 + quad * 8);
            v8s bfr;
            #pragma unroll
            for (int jj = 0; jj < 8; jj++)
                bfr[jj] = Vs[(kc * 32 + quad * 8 + jj) * 64 + wid * 16 + l16];
            oc = __builtin_amdgcn_mfma_f32_16x16x32_bf16(pa, bfr, oc, 0, 0, 0);
        }
        #pragma unroll
        for (int r = 0; r < 4; r++) {
            int i = qt * 16 + quad * 4 + r;
            if (i >= 1 && i <= 48) {
                int sp = typ == 0 ? 1 + n * 48 + (i - 1) : 1 + (i - 1) * 48 + n;
                attn_b[(rowbase + sp) * DIM + hoff + wid * 16 + l16] =
                    __float2bfloat16(oc[r] * invl[i]);
            }
        }
    }
}

// ---------------- nearby attention: K direct-global gather, V in LDS halves ----------------
// blocks 0..2303: attention tiles. blocks 2304..2305: special rows 0/2304 per b.
__global__ __launch_bounds__(256) void nearby_flash(
    const unsigned short* __restrict__ qkvb, const float* __restrict__ colsum,
    __hip_bfloat16* __restrict__ attn_b) {
    __shared__ short Vs[128 * 64];          // 16 KB, one V half (chunk-XOR key=(slot>>3)&7)
    __shared__ __hip_bfloat16 Ps[16 * 264]; // 8.25 KB
    __shared__ float redm[16 * 4];
    __shared__ float reds[16 * 4];

    int tid = threadIdx.x;
    int wid = tid >> 6, lane = tid & 63;
    int quad = lane >> 4, l16 = lane & 15;

    int idx = blockIdx.x;
    if (idx >= 2304) {      // special rows for one b (from GEMM-accumulated colsum)
        int b = idx - 2304;
        size_t rb = (size_t)b * SEQ;
        for (int c = tid; c < 512; c += 256) {
            attn_b[(rb + 2304) * DIM + c] =
                __float2bfloat16(colsum[b * 512 + c] * (1.0f / 2305.0f));
            attn_b[rb * DIM + c] =
                __float2bfloat16(bf2f(qkvb[rb * QKVN + 1024 + c]));
        }
        return;
    }

    int bh = idx & 15;
    int tile = idx >> 4;
    int b = bh >> 3, h = bh & 7;
    int t = tile >> 4;
    int sxy = tile & 15;
    int hh0 = (sxy >> 2) * 4, ww0 = (sxy & 3) * 4;
    int nf = (t < 3 ? t : 3) + 1;
    int t0 = t - (nf - 1);
    size_t rowbase = (size_t)b * SEQ;
    int hoff = h * 64;

    auto slot_kp = [&](int slot) -> int {
        int f = slot >> 6, uy = (slot >> 3) & 7, ux = slot & 7;
        int kh = hh0 - 2 + uy, kw = ww0 - 2 + ux;
        int kt = t0 + f;
        bool ok = (kh >= 0) && (kh < 16) && (kw >= 0) && (kw < 16) && (f < nf);
        return ok ? (kt * 256 + kh * 16 + kw + 1) : 0;
    };

    int qp_f = t * 256 + (hh0 + (l16 >> 2)) * 16 + (ww0 + (l16 & 3));
    const unsigned short* qptr = qkvb + (rowbase + qp_f) * QKVN + hoff + quad * 8;
    v8s qa0 = *(const v8s*)qptr;
    v8s qa1 = *(const v8s*)(qptr + 32);

    v8s kb_lo[4], kb_hi[4];
    #pragma unroll
    for (int k = 0; k < 4; k++) {
        int slot = (wid * 4 + k) * 16 + l16;
        int kp = slot_kp(slot);
        const unsigned short* kr = qkvb + (rowbase + kp) * QKVN + hoff + 512;
        kb_lo[k] = *(const v8s*)(kr + quad * 8);
        kb_hi[k] = *(const v8s*)(kr + 32 + quad * 8);
    }

    #pragma unroll
    for (int it = 0; it < 4; it++) {
        int linear = it * 256 + tid;
        int slot = linear >> 3;
        int cd = linear & 7;
        int cs = cd ^ ((slot >> 3) & 7);
        int kp = slot_kp(slot);
        const unsigned short* src = qkvb + (rowbase + kp) * QKVN + hoff + 1024 + cs * 8;
        load_lds16(src, Vs + it * 2048 + wid * 512 + lane * 8);
    }

    v4f st[4];
    #pragma unroll
    for (int k = 0; k < 4; k++) {
        v4f a = {};
        a = __builtin_amdgcn_mfma_f32_16x16x32_bf16(qa0, kb_lo[k], a, 0, 0, 0);
        a = __builtin_amdgcn_mfma_f32_16x16x32_bf16(qa1, kb_hi[k], a, 0, 0, 0);
        st[k] = a;
    }

    const float NEG = -3.0e38f;
    float sv[4][4];
    float pm[4] = {NEG, NEG, NEG, NEG};
    #pragma unroll
    for (int k = 0; k < 4; k++) {
        int slot = (wid * 4 + k) * 16 + l16;
        int f = slot >> 6, uy = (slot >> 3) & 7, ux = slot & 7;
        int kh = hh0 - 2 + uy, kw = ww0 - 2 + ux;
        bool okb = (kh >= 0) && (kh < 16) && (kw >= 0) && (kw < 16) && (f < nf);
        int dyp2 = uy - quad;
        bool oky = okb && (dyp2 >= 0) && (dyp2 <= 4);
        #pragma unroll
        for (int r = 0; r < 4; r++) {
            int dxp2 = ux - r;
            bool ok = oky && (dxp2 >= 0) && (dxp2 <= 4);
            if (f == nf - 1) ok = ok && (dyp2 * 5 + dxp2 < 12);
            float v = ok ? st[k][r] * 0.125f : NEG;
            sv[k][r] = v;
            pm[r] = fmaxf(pm[r], v);
        }
    }
    #pragma unroll
    for (int r = 0; r < 4; r++)
        for (int o = 1; o < 16; o <<= 1) pm[r] = fmaxf(pm[r], __shfl_xor(pm[r], o));
    if (l16 == 0) {
        #pragma unroll
        for (int r = 0; r < 4; r++) redm[(quad * 4 + r) * 4 + wid] = pm[r];
    }
    __syncthreads();   // barrier 1: redm visible, V half-0 staged

    float rm[4];
    #pragma unroll
    for (int r = 0; r < 4; r++) {
        int row = (quad * 4 + r) * 4;
        rm[r] = fmaxf(fmaxf(redm[row], redm[row + 1]), fmaxf(redm[row + 2], redm[row + 3]));
    }

    float ps[4] = {0.f, 0.f, 0.f, 0.f};
    #pragma unroll
    for (int k = 0; k < 4; k++) {
        int slot = (wid * 4 + k) * 16 + l16;
        #pragma unroll
        for (int r = 0; r < 4; r++) {
            float e = __expf(sv[k][r] - rm[r]);
            ps[r] += e;
            Ps[(quad * 4 + r) * 264 + slot] = __float2bfloat16(e);
        }
    }
    #pragma unroll
    for (int r = 0; r < 4; r++)
        for (int o = 1; o < 16; o <<= 1) ps[r] += __shfl_xor(ps[r], o);
    if (l16 == 0) {
        #pragma unroll
        for (int r = 0; r < 4; r++) reds[(quad * 4 + r) * 4 + wid] = ps[r];
    }
    __syncthreads();   // barrier 2: Ps + reds visible

    float inv[4];
    #pragma unroll
    for (int r = 0; r < 4; r++) {
        int row = (quad * 4 + r) * 4;
        float d = reds[row] + reds[row + 1] + reds[row + 2] + reds[row + 3];
        inv[r] = 1.0f / d;
    }

    int dcol = wid * 16 + l16;
    int c_r = dcol >> 3, d7 = dcol & 7;
    v4f oc = {};
    #pragma unroll
    for (int kc = 0; kc < 4; kc++) {
        v8s pa = *(const v8s*)((const short*)Ps + l16 * 264 + kc * 32 + quad * 8);
        v8s bf;
        #pragma unroll
        for (int j = 0; j < 8; j++) {
            int slot = kc * 32 + quad * 8 + j;
            int key = (slot >> 3) & 7;
            bf[j] = Vs[(slot & 127) * 64 + ((c_r ^ key) * 8) + d7];
        }
        oc = __builtin_amdgcn_mfma_f32_16x16x32_bf16(pa, bf, oc, 0, 0, 0);
    }
    __syncthreads();   // barrier 3: half-0 reads done

    #pragma unroll
    for (int it = 0; it < 4; it++) {
        int linear = 1024 + it * 256 + tid;
        int slot = linear >> 3;
        int cd = linear & 7;
        int cs = cd ^ ((slot >> 3) & 7);
        int kp = slot_kp(slot);
        const unsigned short* src = qkvb + (rowbase + kp) * QKVN + hoff + 1024 + cs * 8;
        load_lds16(src, Vs + it * 2048 + wid * 512 + lane * 8);
    }
    __syncthreads();   // barrier 4: half-1 staged

    #pragma unroll
    for (int kc = 4; kc < 8; kc++) {
        v8s pa = *(const v8s*)((const short*)Ps + l16 * 264 + kc * 32 + quad * 8);
        v8s bf;
        #pragma unroll
        for (int j = 0; j < 8; j++) {
            int slot = kc * 32 + quad * 8 + j;
            int key = (slot >> 3) & 7;
            bf[j] = Vs[(slot & 127) * 64 + ((c_r ^ key) * 8) + d7];
        }
        oc = __builtin_amdgcn_mfma_f32_16x16x32_bf16(pa, bf, oc, 0, 0, 0);
    }

    #pragma unroll
    for (int r = 0; r < 4; r++) {
        int qp = t * 256 + (hh0 + quad) * 16 + (ww0 + r);
        if (qp != 0) {
            attn_b[(rowbase + qp) * DIM + hoff + dcol] =
                __float2bfloat16(oc[r] * inv[r]);
        }
    }
}

// ---------------- host launch ----------------
extern "C" void kernel_launch(void* const* d_in, const int* in_sizes, int n_in,
                              void* d_out, int out_size, void* d_ws, size_t ws_size,
                              hipStream_t stream) {
    const float* x = (const float*)d_in[0];
    float* xcur = (float*)d_out;

    char* ws = (char*)d_ws;
    size_t off = 0;
    auto alloc = [&](size_t bytes) -> void* {
        void* p = ws + off;
        off = (off + bytes + 255) & ~(size_t)255;
        return p;
    };
    __hip_bfloat16* wqkv  = (__hip_bfloat16*)alloc((size_t)3 * QKVN * DIM * 2);
    __hip_bfloat16* wo    = (__hip_bfloat16*)alloc((size_t)3 * DIM * DIM * 2);
    __hip_bfloat16* xb    = (__hip_bfloat16*)alloc((size_t)MPAD * DIM * 2);
    __hip_bfloat16* attnb = (__hip_bfloat16*)alloc((size_t)MPAD * DIM * 2);
    float* colsum         = (float*)alloc((size_t)2 * 512 * 4);
    __hip_bfloat16* qkvb  = (__hip_bfloat16*)alloc((size_t)NROWS * QKVN * 2);

    const int nElem = NROWS * DIM;
    const int n4 = nElem / 4;

    WPack wp;
    for (int l = 0; l < 3; l++)
        for (int j = 0; j < 4; j++)
            wp.p[l * 4 + j] = (const float*)d_in[2 + l * 5 + j];
    prep_inputs<<<dim3(16, 16, 13), dim3(32, 8), 0, stream>>>(
        wp, wqkv, wo, (const float4*)x, xb, n4, colsum);

    for (int l = 0; l < 3; l++) {
        gemm_lds<<<dim3(MPAD / 64, QKVN / 128), 256, 0, stream>>>(
            xb, wqkv + (size_t)l * QKVN * DIM, nullptr, nullptr, nullptr, qkvb,
            NROWS, QKVN, l == 2 ? colsum : nullptr);
        if (l < 2) {
            axial_flash<<<dim3(48, 16), 256, 0, stream>>>((const unsigned short*)qkvb, attnb, l);
        } else {
            nearby_flash<<<2304 + 2, 256, 0, stream>>>(
                (const unsigned short*)qkvb, colsum, attnb);
        }
        const float* bo = (const float*)d_in[6 + l * 5];
        if (l < 2) {
            // residual stream stays bf16: xb <- attnb*Wo + bo + xb (in place)
            gemm_lds<<<dim3(MPAD / 64, DIM / 128), 256, 0, stream>>>(
                attnb, wo + (size_t)l * DIM * DIM, nullptr, bo, xb, xb, NROWS, DIM, nullptr);
        } else {
            // final layer: write fp32 output
            gemm_lds<<<dim3(MPAD / 64, DIM / 128), 256, 0, stream>>>(
                attnb, wo + (size_t)l * DIM * DIM, xcur, bo, xb, nullptr, NROWS, DIM, nullptr);
        }
    }
}